// Round 5
// baseline (79.731 us; speedup 1.0000x reference)
//
#include <hip/hip_runtime.h>
#include <math.h>

// Problem: predict_pc 4x3x4096, gt_pc 4x3x4096 fp32; symmetric 1-NN chamfer mean.
// min d2 = p2+g2-2*p.g  <=>  max score = p.g - g2/2.
// Candidates pre-packed as float4 (x,y,z,-g2/2) in global ws; pass1 reads them
// via wave-uniform (scalar) loads -> no LDS, pure-VALU inner loop, 4 ops/pair.
#define BATCH 4
#define NPTS 4096
#define THREADS 256
#define P 8                            // points per thread
#define SEGS 64                        // candidate segments
#define CSEG (NPTS / SEGS)             // 64 candidates per segment
#define PTGRPS (NPTS / (THREADS * P))  // 2 point-groups per (dir,batch)
#define PASS1_BLOCKS (2 * BATCH * PTGRPS * SEGS)   // 1024 -> 4 waves/SIMD, 256 CUs
#define TOTAL_PTS (2 * BATCH * NPTS)   // 32768
#define PASS2_BLOCKS 128
#define PACK_BLOCKS (TOTAL_PTS / THREADS)          // 128

#define EPS 1e-8f
#define BIG 1e30f

// ws layout: pmin[SEGS][TOTAL_PTS] (8MB, every slot written) ;
//            packed[2][BATCH][NPTS] float4 (512KB) ; acc (float) ; ctr (int).
#define PMIN_FLOATS ((size_t)SEGS * TOTAL_PTS)

// Pack kernel: packed[(dir*BATCH+batch)*NPTS + n] = (x, y, z, -0.5*g2) of the
// CANDIDATE cloud for that direction (dir0: gt, dir1: pred). Also inits acc/ctr
// (stream-ordered before pass2 uses them; redone every call — re-poison safe).
__global__ __launch_bounds__(THREADS) void chamfer_pack(
    const float* __restrict__ pred, const float* __restrict__ gt,
    float4* __restrict__ packed, float* __restrict__ acc, int* __restrict__ ctr)
{
    if (blockIdx.x == 0 && threadIdx.x == 0) { acc[0] = 0.0f; ctr[0] = 0; }
    const int i     = blockIdx.x * THREADS + threadIdx.x;   // [0, 32768)
    const int n     = i & (NPTS - 1);
    const int batch = (i >> 12) & (BATCH - 1);
    const int dir   = i >> 14;
    const float* src = (dir == 0) ? gt : pred;              // candidates for this dir
    const float* cb  = src + (size_t)batch * 3 * NPTS;
    const float x = cb[n];
    const float y = cb[NPTS + n];
    const float z = cb[2 * NPTS + n];
    const float w = -0.5f * fmaf(x, x, fmaf(y, y, z * z));
    packed[i] = make_float4(x, y, z, w);
}

// Pass 1: block = (dir, batch, point-group of 2048 pts, candidate-segment of 64).
// Candidates read via wave-uniform loads (scalar path); inner loop pure VALU.
__global__ __launch_bounds__(THREADS) void chamfer_pass1(
    const float* __restrict__ pred, const float* __restrict__ gt,
    const float4* __restrict__ packed, float* __restrict__ pmin)
{
    const int bid   = blockIdx.x;
    const int seg   = bid & (SEGS - 1);
    const int ptgrp = (bid >> 6) & (PTGRPS - 1);
    const int batch = (bid >> 7) & (BATCH - 1);
    const int dir   = bid >> 9;

    const float* pts = (dir == 0) ? pred : gt;

    // This thread's 8 points (coalesced, stride-256 within the 2048-pt group).
    const float* pb = pts + (size_t)batch * 3 * NPTS;
    const int pbase = ptgrp * (THREADS * P) + threadIdx.x;
    float px[P], py[P], pz[P], smax[P];
    #pragma unroll
    for (int k = 0; k < P; ++k) {
        const int i = pbase + k * THREADS;
        px[k] = pb[i];
        py[k] = pb[NPTS + i];
        pz[k] = pb[2 * NPTS + i];
        smax[k] = -BIG;
    }

    // 64 candidates, wave-uniform address -> s_load (scalar cache, no LDS/VMEM).
    const float4* __restrict__ cp =
        packed + ((size_t)(dir * BATCH + batch) * NPTS + seg * CSEG);

    #pragma unroll 4
    for (int g = 0; g < CSEG / 4; ++g) {
        const float4 c0 = cp[4 * g + 0];
        const float4 c1 = cp[4 * g + 1];
        const float4 c2 = cp[4 * g + 2];
        const float4 c3 = cp[4 * g + 3];
        #pragma unroll
        for (int k = 0; k < P; ++k) {
            float t0 = fmaf(px[k], c0.x, fmaf(py[k], c0.y, fmaf(pz[k], c0.z, c0.w)));
            float t1 = fmaf(px[k], c1.x, fmaf(py[k], c1.y, fmaf(pz[k], c1.z, c1.w)));
            float t2 = fmaf(px[k], c2.x, fmaf(py[k], c2.y, fmaf(pz[k], c2.z, c2.w)));
            float t3 = fmaf(px[k], c3.x, fmaf(py[k], c3.y, fmaf(pz[k], c3.z, c3.w)));
            smax[k] = fmaxf(smax[k], fmaxf(fmaxf(t0, t1), fmaxf(t2, t3)));
        }
    }

    // Convert to d2 and store: pmin[seg][global_point], coalesced per k.
    const int gp = dir * (BATCH * NPTS) + batch * NPTS + pbase;
    #pragma unroll
    for (int k = 0; k < P; ++k) {
        const float p2 = fmaf(px[k], px[k], fmaf(py[k], py[k], pz[k] * pz[k]));
        pmin[(size_t)seg * TOTAL_PTS + gp + k * THREADS] = fmaf(-2.0f, smax[k], p2);
    }
}

// Pass 2 (fused finalize): per point min over 64 segment d2s, clamp, sqrt(+eps),
// block-sum, atomic-accumulate; last-arriving block writes the scalar mean.
__global__ __launch_bounds__(THREADS) void chamfer_pass2(
    const float* __restrict__ pmin, float* __restrict__ acc, int* __restrict__ ctr,
    float* __restrict__ out)
{
    const int p = blockIdx.x * THREADS + threadIdx.x;   // one point per thread
    float v = BIG;
    #pragma unroll
    for (int s = 0; s < SEGS; ++s)
        v = fminf(v, pmin[(size_t)s * TOTAL_PTS + p]);
    float r = sqrtf(fmaxf(v, 0.0f) + EPS);

    #pragma unroll
    for (int off = 32; off; off >>= 1) r += __shfl_down(r, off, 64);
    __shared__ float wsum[THREADS / 64];
    if ((threadIdx.x & 63) == 0) wsum[threadIdx.x >> 6] = r;
    __syncthreads();

    if (threadIdx.x == 0) {
        const float bs = (wsum[0] + wsum[1]) + (wsum[2] + wsum[3]);
        atomicAdd(acc, bs);                 // device-scope by default
        __threadfence();
        const int t = atomicAdd(ctr, 1);
        if (t == PASS2_BLOCKS - 1) {
            __threadfence();
            const float total = atomicAdd(acc, 0.0f);   // atomic read of final sum
            out[0] = total * (1.0f / (float)(BATCH * NPTS));
        }
    }
}

extern "C" void kernel_launch(void* const* d_in, const int* in_sizes, int n_in,
                              void* d_out, int out_size, void* d_ws, size_t ws_size,
                              hipStream_t stream) {
    const float* pred = (const float*)d_in[0];
    const float* gt   = (const float*)d_in[1];
    float*  out    = (float*)d_out;
    float*  pmin   = (float*)d_ws;                    // 8MB, every slot written
    float4* packed = (float4*)(pmin + PMIN_FLOATS);   // 512KB packed candidates
    float*  acc    = (float*)(packed + TOTAL_PTS);    // scalar accumulator
    int*    ctr    = (int*)(acc + 1);                 // arrival counter

    chamfer_pack <<<PACK_BLOCKS,  THREADS, 0, stream>>>(pred, gt, packed, acc, ctr);
    chamfer_pass1<<<PASS1_BLOCKS, THREADS, 0, stream>>>(pred, gt, packed, pmin);
    chamfer_pass2<<<PASS2_BLOCKS, THREADS, 0, stream>>>(pmin, acc, ctr, out);
}

// Round 6
// 70.644 us; speedup vs baseline: 1.1286x; 1.1286x over previous
//
#include <hip/hip_runtime.h>
#include <math.h>

// Problem: predict_pc 4x3x4096, gt_pc 4x3x4096 fp32; symmetric 1-NN chamfer mean.
// Inner-loop math: min d2 = p2+g2-2*p.g  <=>  max score = p.g - g2/2.
// Candidates staged in LDS as float4 (x, y, z, -g2/2) -> 3 fma + 1 max per pair.
// R3 structure (measured best 71.5us); pass2 widened to 128 blocks; unroll 4.
#define BATCH 4
#define NPTS 4096
#define THREADS 256
#define P 8                          // points per thread
#define SEGS 32                      // candidate segments
#define CSEG (NPTS / SEGS)           // 128 candidates per segment
#define PTGRPS (NPTS / (THREADS * P))        // 2 point-groups per (dir,batch)
#define PASS1_BLOCKS (2 * BATCH * PTGRPS * SEGS)  // 512 -> 2 blocks/CU, 8 waves/CU
#define TOTAL_PTS (2 * BATCH * NPTS)         // 32768
#define PASS2_BLOCKS 128                     // one point per thread

#define EPS 1e-8f
#define BIG 1e30f

// ws layout: [0 .. SEGS*TOTAL_PTS) partial d2 mins (4MB); then PASS2_BLOCKS sums.
#define PMIN_FLOATS ((size_t)SEGS * TOTAL_PTS)

__global__ __launch_bounds__(THREADS) void chamfer_pass1(
    const float* __restrict__ pred, const float* __restrict__ gt,
    float* __restrict__ pmin)
{
    __shared__ float4 lc[CSEG];   // (x, y, z, -0.5*g2) per candidate

    const int bid   = blockIdx.x;
    const int seg   = bid & (SEGS - 1);
    const int ptgrp = (bid >> 5) & (PTGRPS - 1);
    const int batch = (bid >> 6) & (BATCH - 1);
    const int dir   = bid >> 8;

    const float* pts  = (dir == 0) ? pred : gt;
    const float* cand = (dir == 0) ? gt   : pred;

    // Stage this segment's 128 candidates (threads 0..127), computing -g2/2.
    if (threadIdx.x < CSEG) {
        const float* cb = cand + (size_t)batch * 3 * NPTS + seg * CSEG;
        const float x = cb[threadIdx.x];
        const float y = cb[NPTS + threadIdx.x];
        const float z = cb[2 * NPTS + threadIdx.x];
        const float s = -0.5f * fmaf(x, x, fmaf(y, y, z * z));
        lc[threadIdx.x] = make_float4(x, y, z, s);
    }
    __syncthreads();

    // This thread's 8 points (coalesced, stride-256 within the 2048-pt group).
    const float* pb = pts + (size_t)batch * 3 * NPTS;
    const int pbase = ptgrp * (THREADS * P) + threadIdx.x;
    float px[P], py[P], pz[P], smax[P];
    #pragma unroll
    for (int k = 0; k < P; ++k) {
        const int i = pbase + k * THREADS;
        px[k] = pb[i];
        py[k] = pb[NPTS + i];
        pz[k] = pb[2 * NPTS + i];
        smax[k] = -BIG;
    }

    // 32 groups of 4 candidates: 4 ds_read_b128 (broadcast) + 4*P*(3 fma)
    // + P max3-tree per group. unroll 4 keeps >=2 groups of LDS reads in flight.
    #pragma unroll 4
    for (int g = 0; g < CSEG / 4; ++g) {
        const float4 c0 = lc[4 * g + 0];
        const float4 c1 = lc[4 * g + 1];
        const float4 c2 = lc[4 * g + 2];
        const float4 c3 = lc[4 * g + 3];
        #pragma unroll
        for (int k = 0; k < P; ++k) {
            float t0 = fmaf(px[k], c0.x, fmaf(py[k], c0.y, fmaf(pz[k], c0.z, c0.w)));
            float t1 = fmaf(px[k], c1.x, fmaf(py[k], c1.y, fmaf(pz[k], c1.z, c1.w)));
            float t2 = fmaf(px[k], c2.x, fmaf(py[k], c2.y, fmaf(pz[k], c2.z, c2.w)));
            float t3 = fmaf(px[k], c3.x, fmaf(py[k], c3.y, fmaf(pz[k], c3.z, c3.w)));
            // v_max3-friendly tree: max3(t0,t1,t2), then max3(that,t3,smax)
            smax[k] = fmaxf(fmaxf(fmaxf(t0, t1), t2), fmaxf(t3, smax[k]));
        }
    }

    // Convert back to d2 and store: pmin[seg][global_point], coalesced per k.
    const int gp = dir * (BATCH * NPTS) + batch * NPTS + pbase;
    #pragma unroll
    for (int k = 0; k < P; ++k) {
        const float p2 = fmaf(px[k], px[k], fmaf(py[k], py[k], pz[k] * pz[k]));
        pmin[(size_t)seg * TOTAL_PTS + gp + k * THREADS] = fmaf(-2.0f, smax[k], p2);
    }
}

// Pass 2: one point per thread; min over 32 segment d2s, clamp, sqrt(+eps), block-sum.
__global__ __launch_bounds__(THREADS) void chamfer_pass2(
    const float* __restrict__ pmin, float* __restrict__ bsum)
{
    const int p = blockIdx.x * THREADS + threadIdx.x;
    float v = BIG;
    #pragma unroll
    for (int s = 0; s < SEGS; ++s)
        v = fminf(v, pmin[(size_t)s * TOTAL_PTS + p]);
    float r = sqrtf(fmaxf(v, 0.0f) + EPS);

    #pragma unroll
    for (int off = 32; off; off >>= 1) r += __shfl_down(r, off, 64);
    __shared__ float wsum[THREADS / 64];
    if ((threadIdx.x & 63) == 0) wsum[threadIdx.x >> 6] = r;
    __syncthreads();
    if (threadIdx.x == 0)
        bsum[blockIdx.x] = (wsum[0] + wsum[1]) + (wsum[2] + wsum[3]);
}

// Pass 3: reduce 128 block sums; both means share denominator B*NPTS = 16384.
__global__ void chamfer_pass3(const float* __restrict__ bsum, float* __restrict__ out)
{
    float v = bsum[threadIdx.x];
    #pragma unroll
    for (int off = 32; off; off >>= 1) v += __shfl_down(v, off, 64);
    __shared__ float s[2];
    if ((threadIdx.x & 63) == 0) s[threadIdx.x >> 6] = v;
    __syncthreads();
    if (threadIdx.x == 0)
        out[0] = (s[0] + s[1]) * (1.0f / (float)(BATCH * NPTS));
}

extern "C" void kernel_launch(void* const* d_in, const int* in_sizes, int n_in,
                              void* d_out, int out_size, void* d_ws, size_t ws_size,
                              hipStream_t stream) {
    const float* pred = (const float*)d_in[0];
    const float* gt   = (const float*)d_in[1];
    float* out  = (float*)d_out;
    float* pmin = (float*)d_ws;              // 4MB partial d2 mins (all slots written)
    float* bsum = pmin + PMIN_FLOATS;        // 128 block sums

    chamfer_pass1<<<PASS1_BLOCKS, THREADS, 0, stream>>>(pred, gt, pmin);
    chamfer_pass2<<<PASS2_BLOCKS, THREADS, 0, stream>>>(pmin, bsum);
    chamfer_pass3<<<1, 128, 0, stream>>>(bsum, out);
}